// Round 17
// baseline (140.741 us; speedup 1.0000x reference)
//
#include <hip/hip_runtime.h>
#include <hip/hip_bf16.h>
#include <cstddef>
#include <math.h>

// ---------------------------------------------------------------------------
// Model constants
// ---------------------------------------------------------------------------
#define S_LEN 1024
#define D_DIM 128
#define H_HEADS 8
#define FF_DIM 2048
#define L_LAYERS 4
#define HID_DIM 768
#define LN_EPS 1e-5f

#define FF2_KS 8                  // FF2 split-K chunks (tail1 z-dim; 2 blk/CU)
#define FF_KC (FF_DIM / FF2_KS)   // 256 h-cols per fused block

typedef __attribute__((ext_vector_type(8))) short bf16x8;
typedef __attribute__((ext_vector_type(4))) short bf16x4;
typedef __attribute__((ext_vector_type(4))) float f32x4;

// bf16 (as short bits) -> f32 : 16-bit left shift
__device__ __forceinline__ float bf16s_to_f(short s)
{
    return __uint_as_float(((unsigned int)(unsigned short)s) << 16);
}
__device__ __forceinline__ short f_to_bf16s(float v)
{
    __hip_bfloat16 hb = __float2bfloat16(v);
    return *reinterpret_cast<short*>(&hb);
}

// ---------------------------------------------------------------------------
// Wave-level MFMA tile: 16 rows x (NT*16) cols (proven fragment layout:
// A row = l&15, k-offset = (l>>4)*8; C/D row = (l>>4)*4+j, col = l&15).
// ---------------------------------------------------------------------------
template<int NT>
__device__ __forceinline__ void mfma_tile(
    const __hip_bfloat16* __restrict__ A, const __hip_bfloat16* __restrict__ W,
    int K, int m0, int n0, int kbeg, int kend, int lane, f32x4* acc)
{
    const int lr = lane & 15;
    const int lk = (lane >> 4) * 8;
    const __hip_bfloat16* Ap = A + (size_t)(m0 + lr) * K + lk;
    const __hip_bfloat16* Wp = W + (size_t)(n0 + lr) * K + lk;
    #pragma unroll 4
    for (int k = kbeg; k < kend; k += 32) {
        const bf16x8 a = *reinterpret_cast<const bf16x8*>(Ap + k);
        #pragma unroll
        for (int nt = 0; nt < NT; ++nt) {
            const bf16x8 b = *reinterpret_cast<const bf16x8*>(Wp + (size_t)nt * 16 * K + k);
            acc[nt] = __builtin_amdgcn_mfma_f32_16x16x32_bf16(a, b, acc[nt], 0, 0, 0);
        }
    }
}

// ---------------------------------------------------------------------------
// One-shot weight conversion fp32 -> bf16 (concatenated, proven).
// ---------------------------------------------------------------------------
__global__ __launch_bounds__(256) void wconv_kernel(
    const float* __restrict__ Wqkv, const float* __restrict__ Wo,
    const float* __restrict__ W1, const float* __restrict__ W2,
    const float* __restrict__ Wout, __hip_bfloat16* __restrict__ dst)
{
    const int i = blockIdx.x * 256 + threadIdx.x;   // float4 index, 0..614399
    const float* src;
    int off4;
    if (i < 49152)       { src = Wqkv; off4 = i; }
    else if (i < 65536)  { src = Wo;   off4 = i - 49152; }
    else if (i < 327680) { src = W1;   off4 = i - 65536; }
    else if (i < 589824) { src = W2;   off4 = i - 327680; }
    else                 { src = Wout; off4 = i - 589824; }
    const float4 v = reinterpret_cast<const float4*>(src)[off4];
    __hip_bfloat16* o = dst + (size_t)i * 4;
    o[0] = __float2bfloat16(v.x);
    o[1] = __float2bfloat16(v.y);
    o[2] = __float2bfloat16(v.z);
    o[3] = __float2bfloat16(v.w);
}

// ---------------------------------------------------------------------------
// embed + layer-0 QKV, fused (proven). 64 blocks x 1024 thr.
// ---------------------------------------------------------------------------
__global__ __launch_bounds__(1024, 1) void embed_qkv_kernel(
    const int* __restrict__ shot, const int* __restrict__ cam,
    const int* __restrict__ light, const int* __restrict__ tone,
    const int* __restrict__ rhythm, const int* __restrict__ trans,
    const float* __restrict__ motion, const float* __restrict__ focus,
    const float* __restrict__ E_shot, const float* __restrict__ E_cam,
    const float* __restrict__ E_light, const float* __restrict__ E_tone,
    const float* __restrict__ E_rhythm, const float* __restrict__ E_trans,
    const float* __restrict__ W_m1, const float* __restrict__ b_m1,
    const float* __restrict__ W_m2, const float* __restrict__ b_m2,
    const float* __restrict__ W_f, const float* __restrict__ b_f,
    const float* __restrict__ pos,
    const __hip_bfloat16* __restrict__ Wqkv0, const float* __restrict__ bqkv0,
    float* __restrict__ x, __hip_bfloat16* __restrict__ x_bf,
    __hip_bfloat16* __restrict__ qkv_bf)
{
    const int blk = blockIdx.x;
    const int tid = threadIdx.x;
    const int m0  = blk * 16;

    for (int e = tid; e < 16 * D_DIM; e += 1024) {
        const int s = m0 + (e >> 7);
        const int d = e & 127;
        const float4 mp = *reinterpret_cast<const float4*>(motion + s * 4);
        const float f0 = focus[s * 2 + 0], f1 = focus[s * 2 + 1];
        float acc = b_m2[d];
        const float* w2row = W_m2 + (size_t)d * 64;
        #pragma unroll 8
        for (int k2 = 0; k2 < 64; ++k2) {
            const float hk = b_m1[k2]
                + W_m1[k2 * 4 + 0] * mp.x + W_m1[k2 * 4 + 1] * mp.y
                + W_m1[k2 * 4 + 2] * mp.z + W_m1[k2 * 4 + 3] * mp.w;
            acc += w2row[k2] * fmaxf(hk, 0.0f);
        }
        acc += b_f[d] + W_f[d * 2 + 0] * f0 + W_f[d * 2 + 1] * f1;
        acc += E_shot  [(size_t)shot[s]   * D_DIM + d];
        acc += E_cam   [(size_t)cam[s]    * D_DIM + d];
        acc += E_light [(size_t)light[s]  * D_DIM + d];
        acc += E_tone  [(size_t)tone[s]   * D_DIM + d];
        acc += E_rhythm[(size_t)rhythm[s] * D_DIM + d];
        acc += E_trans [(size_t)trans[s]  * D_DIM + d];
        acc += pos[(size_t)s * D_DIM + d];
        const size_t gi = (size_t)s * D_DIM + d;
        x[gi] = acc;
        x_bf[gi] = __float2bfloat16(acc);
    }
    __syncthreads();

    const int wave = tid >> 6, lane = tid & 63;
    for (int u = wave; u < 12; u += 16) {
        const int n0 = u * 32;
        f32x4 acc[2] = {};
        mfma_tile<2>(x_bf, Wqkv0, 128, m0, n0, 0, 128, lane, acc);
        const int orow = m0 + (lane >> 4) * 4;
        #pragma unroll
        for (int h = 0; h < 2; ++h) {
            const int col = n0 + h * 16 + (lane & 15);
            const float bv = bqkv0[col];
            #pragma unroll
            for (int j = 0; j < 4; ++j)
                qkv_bf[(size_t)(orow + j) * 384 + col] =
                    __float2bfloat16(acc[h][j] + bv);
        }
    }
}

// ---------------------------------------------------------------------------
// MFMA attention (swapped QK^T, 16x16x32 intrinsic; proven R16).
// grid (64 q-tiles, 8 heads) = 512 blk x 256 thr (4 waves).
// ---------------------------------------------------------------------------
__global__ __launch_bounds__(256) void attn_mfma_kernel(
    const __hip_bfloat16* __restrict__ qkv, __hip_bfloat16* __restrict__ attn_bf)
{
    __shared__ __hip_bfloat16 pt[4][16][40];   // per-wave P tile [q][32+pad]
    __shared__ float mlds[4][2][16];
    __shared__ float Olds[4][16][17];

    const int t  = threadIdx.x;
    const int w  = t >> 6;
    const int l  = t & 63;
    const int qt = blockIdx.x;      // 16 q-rows each
    const int h  = blockIdx.y;
    const int lq = l & 15;
    const int lg = l >> 4;

    // Q B-frag (dh padded to 32): lanes lg<2 hold Q[q=lq][dh=lg*8+j] * 0.25
    bf16x8 qf = {};
    if (lg < 2) {
        const bf16x8 raw = *reinterpret_cast<const bf16x8*>(
            qkv + (size_t)(qt * 16 + lq) * 384 + h * 16 + lg * 8);
        #pragma unroll
        for (int j = 0; j < 8; ++j)
            qf[j] = f_to_bf16s(bf16s_to_f(raw[j]) * 0.25f);   // exact (pow2)
    }

    float m = -INFINITY, lsum = 0.f;
    f32x4 O = {0.f, 0.f, 0.f, 0.f};
    const f32x4 zero = {0.f, 0.f, 0.f, 0.f};

    const int kw = w * 256;
    for (int ch = 0; ch < 8; ++ch) {
        const int kb = kw + ch * 32;

        // K A-frags for the two 16-key tiles (dh padded to 32)
        bf16x8 kf0 = {}, kf1 = {};
        if (lg < 2) {
            kf0 = *reinterpret_cast<const bf16x8*>(
                qkv + (size_t)(kb + lq) * 384 + 128 + h * 16 + lg * 8);
            kf1 = *reinterpret_cast<const bf16x8*>(
                qkv + (size_t)(kb + 16 + lq) * 384 + 128 + h * 16 + lg * 8);
        }
        const f32x4 s0 = __builtin_amdgcn_mfma_f32_16x16x32_bf16(kf0, qf, zero, 0, 0, 0);
        const f32x4 s1 = __builtin_amdgcn_mfma_f32_16x16x32_bf16(kf1, qf, zero, 0, 0, 0);

        float tm = fmaxf(fmaxf(s0[0], s0[1]), fmaxf(s0[2], s0[3]));
        tm = fmaxf(tm, fmaxf(fmaxf(s1[0], s1[1]), fmaxf(s1[2], s1[3])));
        tm = fmaxf(tm, __shfl_xor(tm, 16));
        tm = fmaxf(tm, __shfl_xor(tm, 32));
        const float mn = fmaxf(m, tm);
        const float corr = __expf(m - mn);
        m = mn;

        float p0[4], p1[4], ts = 0.f;
        #pragma unroll
        for (int j = 0; j < 4; ++j) {
            p0[j] = __expf(s0[j] - m);
            p1[j] = __expf(s1[j] - m);
            ts += p0[j] + p1[j];
        }
        ts += __shfl_xor(ts, 16);
        ts += __shfl_xor(ts, 32);
        lsum = lsum * corr + ts;

        // P -> LDS [q][key] (bf16), then read back as PV A-frag
        #pragma unroll
        for (int j = 0; j < 4; ++j) {
            pt[w][lq][lg * 4 + j]      = __float2bfloat16(p0[j]);
            pt[w][lq][16 + lg * 4 + j] = __float2bfloat16(p1[j]);
        }
        const bf16x8 pa = *reinterpret_cast<const bf16x8*>(&pt[w][lq][lg * 8]);

        // V^T B-frag: lane holds V[key=kb+lg*8+j][dh=lq]
        bf16x8 vf;
        #pragma unroll
        for (int j = 0; j < 8; ++j)
            vf[j] = *reinterpret_cast<const short*>(
                qkv + (size_t)(kb + lg * 8 + j) * 384 + 256 + h * 16 + lq);

        // rescale O rows (row q' = lg*4+j) by corr[q']
        #pragma unroll
        for (int j = 0; j < 4; ++j)
            O[j] *= __shfl(corr, lg * 4 + j);

        O = __builtin_amdgcn_mfma_f32_16x16x32_bf16(pa, vf, O, 0, 0, 0);
    }

    // wave partials
    if (l < 16) { mlds[w][0][l] = m; mlds[w][1][l] = lsum; }
    #pragma unroll
    for (int j = 0; j < 4; ++j)
        Olds[w][lg * 4 + j][lq] = O[j];
    __syncthreads();

    // merge: thread t -> (q = t>>4, dh = t&15)
    {
        const int q = t >> 4, dh = t & 15;
        float mg = -INFINITY;
        #pragma unroll
        for (int ww = 0; ww < 4; ++ww) mg = fmaxf(mg, mlds[ww][0][q]);
        float lg2 = 0.f, ov = 0.f;
        #pragma unroll
        for (int ww = 0; ww < 4; ++ww) {
            const float wgt = __expf(mlds[ww][0][q] - mg);
            lg2 += mlds[ww][1][q] * wgt;
            ov  += wgt * Olds[ww][q][dh];
        }
        attn_bf[(size_t)(qt * 16 + q) * D_DIM + h * 16 + dh] =
            __float2bfloat16(ov / lg2);
    }
}

// ---------------------------------------------------------------------------
// tail1: load attn rows + Wo + residual + LN1 + FF1 + FF2-partial.
// grid (64, FF2_KS=8) = 512 blocks x 512 thr (2 blocks/CU). LDS ~26 KB.
// ---------------------------------------------------------------------------
__global__ __launch_bounds__(512) void tail1_kernel(
    const __hip_bfloat16* __restrict__ attn_g,
    const __hip_bfloat16* __restrict__ Wo_i, const float* __restrict__ bo_i,
    const float* __restrict__ x_in, float* __restrict__ x2,
    const float* __restrict__ g, const float* __restrict__ b,
    const __hip_bfloat16* __restrict__ W1_i, const float* __restrict__ b1_i,
    const __hip_bfloat16* __restrict__ W2_i, float* __restrict__ P)
{
    __shared__ __hip_bfloat16 att[16][136];     // attn rows (bf16)
    __shared__ float lds_wo[16][132];           // Wo output (f32)
    __shared__ __hip_bfloat16 xb[16][136];      // post-LN1 rows (bf16)
    __shared__ __hip_bfloat16 h[16][FF_KC + 8]; // FF1 output (bf16)

    const int t    = threadIdx.x;
    const int wave = t >> 6;
    const int lane = t & 63;
    const int lr   = lane & 15;
    const int lk   = (lane >> 4) * 8;
    const int m0   = blockIdx.x * 16;
    const int kb   = blockIdx.y * FF_KC;

    // ---- A: load attn rows (16 x 128 bf16, 4 per thread) ----
    {
        const int e    = t * 4;          // 0..2044
        const int rloc = e >> 7;
        const int col  = e & 127;
        *reinterpret_cast<bf16x4*>(&att[rloc][col]) =
            *reinterpret_cast<const bf16x4*>(
                attn_g + (size_t)(m0 + rloc) * D_DIM + col);
    }
    __syncthreads();

    // ---- B: Wo (8 col-units of 16 over 8 waves = 1 round) ----
    {
        const int n0 = wave * 16;
        f32x4 acc = {};
        const __hip_bfloat16* Wp = Wo_i + (size_t)(n0 + lr) * 128 + lk;
        #pragma unroll
        for (int k = 0; k < 128; k += 32) {
            const bf16x8 a = *reinterpret_cast<const bf16x8*>(&att[lr][lk + k]);
            const bf16x8 bb = *reinterpret_cast<const bf16x8*>(Wp + k);
            acc = __builtin_amdgcn_mfma_f32_16x16x32_bf16(a, bb, acc, 0, 0, 0);
        }
        const int orow = (lane >> 4) * 4;
        const int col  = n0 + lr;
        #pragma unroll
        for (int j = 0; j < 4; ++j)
            lds_wo[orow + j][col] = acc[j];
    }
    __syncthreads();

    // ---- C: residual + LN1 (16 rows over 8 waves = 2 rounds) ----
    #pragma unroll
    for (int rr = 0; rr < 2; ++rr) {
        const int rloc = wave + rr * 8;
        const int d0 = lane * 2;
        const size_t i0 = (size_t)(m0 + rloc) * D_DIM + d0;
        float v0 = x_in[i0]     + lds_wo[rloc][d0]     + bo_i[d0];
        float v1 = x_in[i0 + 1] + lds_wo[rloc][d0 + 1] + bo_i[d0 + 1];
        float s = v0 + v1;
        #pragma unroll
        for (int off = 32; off >= 1; off >>= 1) s += __shfl_xor(s, off);
        const float mu = s * (1.0f / 128.0f);
        const float q0 = v0 - mu, q1 = v1 - mu;
        float qs = q0 * q0 + q1 * q1;
        #pragma unroll
        for (int off = 32; off >= 1; off >>= 1) qs += __shfl_xor(qs, off);
        const float rs = rsqrtf(qs * (1.0f / 128.0f) + LN_EPS);
        const float r0 = q0 * rs * g[d0] + b[d0];
        const float r1 = q1 * rs * g[d0 + 1] + b[d0 + 1];
        x2[i0] = r0;     x2[i0 + 1] = r1;
        xb[rloc][d0] = __float2bfloat16(r0);
        xb[rloc][d0 + 1] = __float2bfloat16(r1);
    }
    __syncthreads();

    // ---- D: FF1 (+bias+ReLU) from LDS xb -> LDS h (8 units / 8 waves) ----
    {
        const int n0 = kb + wave * 32;
        f32x4 acc[2] = {};
        const __hip_bfloat16* Wp = W1_i + (size_t)(n0 + lr) * 128 + lk;
        #pragma unroll
        for (int k = 0; k < 128; k += 32) {
            const bf16x8 a = *reinterpret_cast<const bf16x8*>(&xb[lr][lk + k]);
            #pragma unroll
            for (int nt = 0; nt < 2; ++nt) {
                const bf16x8 bb = *reinterpret_cast<const bf16x8*>(Wp + (size_t)nt * 16 * 128 + k);
                acc[nt] = __builtin_amdgcn_mfma_f32_16x16x32_bf16(a, bb, acc[nt], 0, 0, 0);
            }
        }
        const int orow = (lane >> 4) * 4;
        #pragma unroll
        for (int hh = 0; hh < 2; ++hh) {
            const int colg = n0 + hh * 16 + lr;      // global col (bias)
            const int coll = colg - kb;              // local LDS col
            const float bv = b1_i[colg];
            #pragma unroll
            for (int j = 0; j < 4; ++j)
                h[orow + j][coll] =
                    __float2bfloat16(fmaxf(acc[hh][j] + bv, 0.f));
        }
    }
    __syncthreads();

    // ---- E: FF2 partial [16 x 128], K = FF_KC(256) from LDS -> P[z] ----
    {
        const int n0 = wave * 16;
        f32x4 acc = {};
        const __hip_bfloat16* Wp = W2_i + (size_t)(n0 + lr) * FF_DIM + kb + lk;
        #pragma unroll
        for (int k = 0; k < FF_KC; k += 32) {
            const bf16x8 a = *reinterpret_cast<const bf16x8*>(&h[lr][lk + k]);
            const bf16x8 bb = *reinterpret_cast<const bf16x8*>(Wp + k);
            acc = __builtin_amdgcn_mfma_f32_16x16x32_bf16(a, bb, acc, 0, 0, 0);
        }
        float* Pz = P + (size_t)blockIdx.y * (S_LEN * D_DIM);
        const int orow = m0 + (lane >> 4) * 4;
        const int col  = n0 + lr;
        #pragma unroll
        for (int j = 0; j < 4; ++j)
            Pz[(size_t)(orow + j) * D_DIM + col] = acc[j];
    }
}

// ---------------------------------------------------------------------------
// LN2 (+FF2_KS partials + bias) then next-layer QKV (or out-proj if LAST).
// grid (64 m-tiles, NZ) x 256 thr (proven R14/R16).
// ---------------------------------------------------------------------------
template<int LAST>
__global__ __launch_bounds__(256) void ln2_qkv_kernel(
    const float* __restrict__ P, const float* __restrict__ b2_i,
    const float* __restrict__ xr, float* __restrict__ xw,
    const float* __restrict__ g, const float* __restrict__ b,
    const __hip_bfloat16* __restrict__ Wn, const float* __restrict__ bn,
    __hip_bfloat16* __restrict__ qkv_bf, float* __restrict__ out)
{
    __shared__ __hip_bfloat16 xb[16][136];

    const int tid  = threadIdx.x;
    const int wave = tid >> 6;
    const int lane = tid & 63;
    const int lr   = lane & 15;
    const int lk   = (lane >> 4) * 8;
    const int m0   = blockIdx.x * 16;

    // ---- LN2: 16 rows over 4 waves = 4 rounds ----
    #pragma unroll
    for (int rr = 0; rr < 4; ++rr) {
        const int rloc = wave + rr * 4;
        const int d0 = lane * 2;
        const size_t i0 = (size_t)(m0 + rloc) * D_DIM + d0;
        float v0 = xr[i0]     + b2_i[d0];
        float v1 = xr[i0 + 1] + b2_i[d0 + 1];
        #pragma unroll
        for (int p = 0; p < FF2_KS; ++p) {
            v0 += P[(size_t)p * (S_LEN * D_DIM) + i0];
            v1 += P[(size_t)p * (S_LEN * D_DIM) + i0 + 1];
        }
        float s = v0 + v1;
        #pragma unroll
        for (int off = 32; off >= 1; off >>= 1) s += __shfl_xor(s, off);
        const float mu = s * (1.0f / 128.0f);
        const float q0 = v0 - mu, q1 = v1 - mu;
        float qs = q0 * q0 + q1 * q1;
        #pragma unroll
        for (int off = 32; off >= 1; off >>= 1) qs += __shfl_xor(qs, off);
        const float rs = rsqrtf(qs * (1.0f / 128.0f) + LN_EPS);
        const float r0 = q0 * rs * g[d0] + b[d0];
        const float r1 = q1 * rs * g[d0 + 1] + b[d0 + 1];
        xw[i0] = r0;     xw[i0 + 1] = r1;      // replicated: identical values
        xb[rloc][d0] = __float2bfloat16(r0);
        xb[rloc][d0 + 1] = __float2bfloat16(r1);
    }
    __syncthreads();

    // ---- one 16x32 MFMA unit per wave, A from LDS ----
    const int unit = blockIdx.y * 4 + wave;   // 0..11 (QKV) or 0..23 (out)
    const int n0 = unit * 32;
    f32x4 acc[2] = {};
    {
        const __hip_bfloat16* Wp = Wn + (size_t)(n0 + lr) * 128 + lk;
        #pragma unroll
        for (int k = 0; k < 128; k += 32) {
            const bf16x8 a = *reinterpret_cast<const bf16x8*>(&xb[lr][lk + k]);
            #pragma unroll
            for (int nt = 0; nt < 2; ++nt) {
                const bf16x8 bb = *reinterpret_cast<const bf16x8*>(Wp + (size_t)nt * 16 * 128 + k);
                acc[nt] = __builtin_amdgcn_mfma_f32_16x16x32_bf16(a, bb, acc[nt], 0, 0, 0);
            }
        }
    }
    const int orow = m0 + (lane >> 4) * 4;
    if (!LAST) {
        #pragma unroll
        for (int h = 0; h < 2; ++h) {
            const int col = n0 + h * 16 + lr;
            const float bv = bn[col];
            #pragma unroll
            for (int j = 0; j < 4; ++j)
                qkv_bf[(size_t)(orow + j) * 384 + col] =
                    __float2bfloat16(acc[h][j] + bv);
        }
    } else {
        #pragma unroll
        for (int h = 0; h < 2; ++h) {
            const int col = n0 + h * 16 + lr;
            const float bv = bn[col];
            #pragma unroll
            for (int j = 0; j < 4; ++j)
                out[(size_t)(orow + j) * HID_DIM + col] = acc[h][j] + bv;
        }
        if (blockIdx.y == 0 && tid < 16)
            out[(size_t)S_LEN * HID_DIM + m0 + tid] = 0.0f;
    }
}

// ---------------------------------------------------------------------------
// Host launch: 14 dispatches.
// ---------------------------------------------------------------------------
extern "C" void kernel_launch(void* const* d_in, const int* in_sizes, int n_in,
                              void* d_out, int out_size, void* d_ws, size_t ws_size,
                              hipStream_t stream)
{
    const int*   shot    = (const int*)  d_in[0];
    const int*   cam     = (const int*)  d_in[1];
    const int*   light   = (const int*)  d_in[2];
    const int*   tone    = (const int*)  d_in[3];
    const int*   rhythm  = (const int*)  d_in[4];
    const int*   trans   = (const int*)  d_in[5];
    const float* motion  = (const float*)d_in[6];
    const float* focus   = (const float*)d_in[7];
    const float* E_shot  = (const float*)d_in[8];
    const float* E_cam   = (const float*)d_in[9];
    const float* E_light = (const float*)d_in[10];
    const float* E_tone  = (const float*)d_in[11];
    const float* E_rhyth = (const float*)d_in[12];
    const float* E_trans = (const float*)d_in[13];
    const float* W_m1    = (const float*)d_in[14];
    const float* b_m1    = (const float*)d_in[15];
    const float* W_m2    = (const float*)d_in[16];
    const float* b_m2    = (const float*)d_in[17];
    const float* W_f     = (const float*)d_in[18];
    const float* b_f     = (const float*)d_in[19];
    const float* pos     = (const float*)d_in[20];
    const float* Wqkv    = (const float*)d_in[21];
    const float* bqkv    = (const float*)d_in[22];
    const float* Wo      = (const float*)d_in[23];
    const float* bo      = (const float*)d_in[24];
    const float* W1      = (const float*)d_in[25];
    const float* b1      = (const float*)d_in[26];
    const float* W2      = (const float*)d_in[27];
    const float* b2      = (const float*)d_in[28];
    const float* ln1_g   = (const float*)d_in[29];
    const float* ln1_b   = (const float*)d_in[30];
    const float* ln2_g   = (const float*)d_in[31];
    const float* ln2_b   = (const float*)d_in[32];
    const float* W_out   = (const float*)d_in[33];
    const float* b_out   = (const float*)d_in[34];

    float* out = (float*)d_out;

    // workspace layout (ws = 256 MiB, ample)
    float* ws = (float*)d_ws;
    float* x  = ws;                                 // 131072 f32 (pre-LN1 residual)
    float* x2 = x + S_LEN * D_DIM;                  // 131072 f32 (post-LN1 residual)
    float* P  = x2 + S_LEN * D_DIM;                 // 8*131072 (FF2 partials)
    __hip_bfloat16* bfb = (__hip_bfloat16*)(P + FF2_KS * S_LEN * D_DIM);
    __hip_bfloat16* wqkv_bf = bfb;                  // [4][384][128]
    __hip_bfloat16* wo_bf   = wqkv_bf + 196608;     // [4][128][128]
    __hip_bfloat16* w1_bf   = wo_bf   + 65536;      // [4][2048][128]
    __hip_bfloat16* w2_bf   = w1_bf   + 1048576;    // [4][128][2048]
    __hip_bfloat16* wout_bf = w2_bf   + 1048576;    // [768][128]
    __hip_bfloat16* x_bf    = wout_bf + 98304;      // [1024][128] (embed only)
    __hip_bfloat16* qkv_bf  = x_bf    + 131072;     // [1024][384]
    __hip_bfloat16* attn_bf = qkv_bf  + 393216;     // [1024][128]

    // 1) weights -> bf16
    wconv_kernel<<<2400, 256, 0, stream>>>(Wqkv, Wo, W1, W2, W_out, bfb);

    // 2) embed + layer-0 qkv
    embed_qkv_kernel<<<64, 1024, 0, stream>>>(
        shot, cam, light, tone, rhythm, trans, motion, focus,
        E_shot, E_cam, E_light, E_tone, E_rhyth, E_trans,
        W_m1, b_m1, W_m2, b_m2, W_f, b_f, pos,
        wqkv_bf, bqkv, x, x_bf, qkv_bf);

    // 3) layers: 3 dispatches each
    for (int li = 0; li < L_LAYERS; ++li) {
        const __hip_bfloat16* Wo_i = wo_bf + (size_t)li * D_DIM * D_DIM;
        const __hip_bfloat16* W1_i = w1_bf + (size_t)li * FF_DIM * D_DIM;
        const __hip_bfloat16* W2_i = w2_bf + (size_t)li * D_DIM * FF_DIM;
        const float* bo_i = bo + (size_t)li * D_DIM;
        const float* b1_i = b1 + (size_t)li * FF_DIM;
        const float* b2_i = b2 + (size_t)li * D_DIM;
        const float* l1g = ln1_g + (size_t)li * D_DIM;
        const float* l1b = ln1_b + (size_t)li * D_DIM;
        const float* l2g = ln2_g + (size_t)li * D_DIM;
        const float* l2b = ln2_b + (size_t)li * D_DIM;

        attn_mfma_kernel<<<dim3(64, H_HEADS), 256, 0, stream>>>(qkv_bf, attn_bf);

        tail1_kernel<<<dim3(64, FF2_KS), 512, 0, stream>>>(
            attn_bf, Wo_i, bo_i, x, x2, l1g, l1b, W1_i, b1_i, W2_i, P);

        if (li < L_LAYERS - 1) {
            const __hip_bfloat16* Wn = wqkv_bf + (size_t)(li + 1) * 3 * D_DIM * D_DIM;
            const float* bn = bqkv + (size_t)(li + 1) * 3 * D_DIM;
            ln2_qkv_kernel<0><<<dim3(64, 3), 256, 0, stream>>>(
                P, b2_i, x2, x, l2g, l2b, Wn, bn, qkv_bf, nullptr);
        } else {
            ln2_qkv_kernel<1><<<dim3(64, 6), 256, 0, stream>>>(
                P, b2_i, x2, x, l2g, l2b, wout_bf, b_out, nullptr, out);
        }
    }
}

// Round 18
// 134.332 us; speedup vs baseline: 1.0477x; 1.0477x over previous
//
#include <hip/hip_runtime.h>
#include <hip/hip_bf16.h>
#include <cstddef>
#include <math.h>

// ---------------------------------------------------------------------------
// Model constants
// ---------------------------------------------------------------------------
#define S_LEN 1024
#define D_DIM 128
#define H_HEADS 8
#define FF_DIM 2048
#define L_LAYERS 4
#define HID_DIM 768
#define LN_EPS 1e-5f

#define FF2_KS 4                  // FF2 split-K chunks (fused kernel z-dim)
#define FF_KC (FF_DIM / FF2_KS)   // 512 h-cols per fused block

typedef __attribute__((ext_vector_type(8))) short bf16x8;
typedef __attribute__((ext_vector_type(4))) short bf16x4;
typedef __attribute__((ext_vector_type(4))) float f32x4;

// bf16 (as short bits) -> f32 : 16-bit left shift
__device__ __forceinline__ float bf16s_to_f(short s)
{
    return __uint_as_float(((unsigned int)(unsigned short)s) << 16);
}
__device__ __forceinline__ short f_to_bf16s(float v)
{
    __hip_bfloat16 hb = __float2bfloat16(v);
    return *reinterpret_cast<short*>(&hb);
}

// ---------------------------------------------------------------------------
// Wave-level MFMA tile: 16 rows x (NT*16) cols (proven fragment layout:
// A row = l&15, k-offset = (l>>4)*8; C/D row = (l>>4)*4+j, col = l&15).
// ---------------------------------------------------------------------------
template<int NT>
__device__ __forceinline__ void mfma_tile(
    const __hip_bfloat16* __restrict__ A, const __hip_bfloat16* __restrict__ W,
    int K, int m0, int n0, int kbeg, int kend, int lane, f32x4* acc)
{
    const int lr = lane & 15;
    const int lk = (lane >> 4) * 8;
    const __hip_bfloat16* Ap = A + (size_t)(m0 + lr) * K + lk;
    const __hip_bfloat16* Wp = W + (size_t)(n0 + lr) * K + lk;
    #pragma unroll 4
    for (int k = kbeg; k < kend; k += 32) {
        const bf16x8 a = *reinterpret_cast<const bf16x8*>(Ap + k);
        #pragma unroll
        for (int nt = 0; nt < NT; ++nt) {
            const bf16x8 b = *reinterpret_cast<const bf16x8*>(Wp + (size_t)nt * 16 * K + k);
            acc[nt] = __builtin_amdgcn_mfma_f32_16x16x32_bf16(a, b, acc[nt], 0, 0, 0);
        }
    }
}

// ---------------------------------------------------------------------------
// One-shot weight conversion fp32 -> bf16 (concatenated, proven).
// ---------------------------------------------------------------------------
__global__ __launch_bounds__(256) void wconv_kernel(
    const float* __restrict__ Wqkv, const float* __restrict__ Wo,
    const float* __restrict__ W1, const float* __restrict__ W2,
    const float* __restrict__ Wout, __hip_bfloat16* __restrict__ dst)
{
    const int i = blockIdx.x * 256 + threadIdx.x;   // float4 index, 0..614399
    const float* src;
    int off4;
    if (i < 49152)       { src = Wqkv; off4 = i; }
    else if (i < 65536)  { src = Wo;   off4 = i - 49152; }
    else if (i < 327680) { src = W1;   off4 = i - 65536; }
    else if (i < 589824) { src = W2;   off4 = i - 327680; }
    else                 { src = Wout; off4 = i - 589824; }
    const float4 v = reinterpret_cast<const float4*>(src)[off4];
    __hip_bfloat16* o = dst + (size_t)i * 4;
    o[0] = __float2bfloat16(v.x);
    o[1] = __float2bfloat16(v.y);
    o[2] = __float2bfloat16(v.z);
    o[3] = __float2bfloat16(v.w);
}

// ---------------------------------------------------------------------------
// embed + layer-0 QKV, fused (proven). 64 blocks x 1024 thr.
// ---------------------------------------------------------------------------
__global__ __launch_bounds__(1024, 1) void embed_qkv_kernel(
    const int* __restrict__ shot, const int* __restrict__ cam,
    const int* __restrict__ light, const int* __restrict__ tone,
    const int* __restrict__ rhythm, const int* __restrict__ trans,
    const float* __restrict__ motion, const float* __restrict__ focus,
    const float* __restrict__ E_shot, const float* __restrict__ E_cam,
    const float* __restrict__ E_light, const float* __restrict__ E_tone,
    const float* __restrict__ E_rhythm, const float* __restrict__ E_trans,
    const float* __restrict__ W_m1, const float* __restrict__ b_m1,
    const float* __restrict__ W_m2, const float* __restrict__ b_m2,
    const float* __restrict__ W_f, const float* __restrict__ b_f,
    const float* __restrict__ pos,
    const __hip_bfloat16* __restrict__ Wqkv0, const float* __restrict__ bqkv0,
    float* __restrict__ x, __hip_bfloat16* __restrict__ x_bf,
    __hip_bfloat16* __restrict__ qkv_bf)
{
    const int blk = blockIdx.x;
    const int tid = threadIdx.x;
    const int m0  = blk * 16;

    for (int e = tid; e < 16 * D_DIM; e += 1024) {
        const int s = m0 + (e >> 7);
        const int d = e & 127;
        const float4 mp = *reinterpret_cast<const float4*>(motion + s * 4);
        const float f0 = focus[s * 2 + 0], f1 = focus[s * 2 + 1];
        float acc = b_m2[d];
        const float* w2row = W_m2 + (size_t)d * 64;
        #pragma unroll 8
        for (int k2 = 0; k2 < 64; ++k2) {
            const float hk = b_m1[k2]
                + W_m1[k2 * 4 + 0] * mp.x + W_m1[k2 * 4 + 1] * mp.y
                + W_m1[k2 * 4 + 2] * mp.z + W_m1[k2 * 4 + 3] * mp.w;
            acc += w2row[k2] * fmaxf(hk, 0.0f);
        }
        acc += b_f[d] + W_f[d * 2 + 0] * f0 + W_f[d * 2 + 1] * f1;
        acc += E_shot  [(size_t)shot[s]   * D_DIM + d];
        acc += E_cam   [(size_t)cam[s]    * D_DIM + d];
        acc += E_light [(size_t)light[s]  * D_DIM + d];
        acc += E_tone  [(size_t)tone[s]   * D_DIM + d];
        acc += E_rhythm[(size_t)rhythm[s] * D_DIM + d];
        acc += E_trans [(size_t)trans[s]  * D_DIM + d];
        acc += pos[(size_t)s * D_DIM + d];
        const size_t gi = (size_t)s * D_DIM + d;
        x[gi] = acc;
        x_bf[gi] = __float2bfloat16(acc);
    }
    __syncthreads();

    const int wave = tid >> 6, lane = tid & 63;
    for (int u = wave; u < 12; u += 16) {
        const int n0 = u * 32;
        f32x4 acc[2] = {};
        mfma_tile<2>(x_bf, Wqkv0, 128, m0, n0, 0, 128, lane, acc);
        const int orow = m0 + (lane >> 4) * 4;
        #pragma unroll
        for (int h = 0; h < 2; ++h) {
            const int col = n0 + h * 16 + (lane & 15);
            const float bv = bqkv0[col];
            #pragma unroll
            for (int j = 0; j < 4; ++j)
                qkv_bf[(size_t)(orow + j) * 384 + col] =
                    __float2bfloat16(acc[h][j] + bv);
        }
    }
}

// ---------------------------------------------------------------------------
// MFMA attention (swapped QK^T, 16x16x32 intrinsic; proven R16).
// grid (64 q-tiles, 8 heads) = 512 blk x 256 thr (4 waves).
// ---------------------------------------------------------------------------
__global__ __launch_bounds__(256) void attn_mfma_kernel(
    const __hip_bfloat16* __restrict__ qkv, __hip_bfloat16* __restrict__ attn_bf)
{
    __shared__ __hip_bfloat16 pt[4][16][40];   // per-wave P tile [q][32+pad]
    __shared__ float mlds[4][2][16];
    __shared__ float Olds[4][16][17];

    const int t  = threadIdx.x;
    const int w  = t >> 6;
    const int l  = t & 63;
    const int qt = blockIdx.x;      // 16 q-rows each
    const int h  = blockIdx.y;
    const int lq = l & 15;
    const int lg = l >> 4;

    // Q B-frag (dh padded to 32): lanes lg<2 hold Q[q=lq][dh=lg*8+j] * 0.25
    bf16x8 qf = {};
    if (lg < 2) {
        const bf16x8 raw = *reinterpret_cast<const bf16x8*>(
            qkv + (size_t)(qt * 16 + lq) * 384 + h * 16 + lg * 8);
        #pragma unroll
        for (int j = 0; j < 8; ++j)
            qf[j] = f_to_bf16s(bf16s_to_f(raw[j]) * 0.25f);   // exact (pow2)
    }

    float m = -INFINITY, lsum = 0.f;
    f32x4 O = {0.f, 0.f, 0.f, 0.f};
    const f32x4 zero = {0.f, 0.f, 0.f, 0.f};

    const int kw = w * 256;
    for (int ch = 0; ch < 8; ++ch) {
        const int kb = kw + ch * 32;

        // K A-frags for the two 16-key tiles (dh padded to 32)
        bf16x8 kf0 = {}, kf1 = {};
        if (lg < 2) {
            kf0 = *reinterpret_cast<const bf16x8*>(
                qkv + (size_t)(kb + lq) * 384 + 128 + h * 16 + lg * 8);
            kf1 = *reinterpret_cast<const bf16x8*>(
                qkv + (size_t)(kb + 16 + lq) * 384 + 128 + h * 16 + lg * 8);
        }
        const f32x4 s0 = __builtin_amdgcn_mfma_f32_16x16x32_bf16(kf0, qf, zero, 0, 0, 0);
        const f32x4 s1 = __builtin_amdgcn_mfma_f32_16x16x32_bf16(kf1, qf, zero, 0, 0, 0);

        float tm = fmaxf(fmaxf(s0[0], s0[1]), fmaxf(s0[2], s0[3]));
        tm = fmaxf(tm, fmaxf(fmaxf(s1[0], s1[1]), fmaxf(s1[2], s1[3])));
        tm = fmaxf(tm, __shfl_xor(tm, 16));
        tm = fmaxf(tm, __shfl_xor(tm, 32));
        const float mn = fmaxf(m, tm);
        const float corr = __expf(m - mn);
        m = mn;

        float p0[4], p1[4], ts = 0.f;
        #pragma unroll
        for (int j = 0; j < 4; ++j) {
            p0[j] = __expf(s0[j] - m);
            p1[j] = __expf(s1[j] - m);
            ts += p0[j] + p1[j];
        }
        ts += __shfl_xor(ts, 16);
        ts += __shfl_xor(ts, 32);
        lsum = lsum * corr + ts;

        // P -> LDS [q][key] (bf16), then read back as PV A-frag
        #pragma unroll
        for (int j = 0; j < 4; ++j) {
            pt[w][lq][lg * 4 + j]      = __float2bfloat16(p0[j]);
            pt[w][lq][16 + lg * 4 + j] = __float2bfloat16(p1[j]);
        }
        const bf16x8 pa = *reinterpret_cast<const bf16x8*>(&pt[w][lq][lg * 8]);

        // V^T B-frag: lane holds V[key=kb+lg*8+j][dh=lq]
        bf16x8 vf;
        #pragma unroll
        for (int j = 0; j < 8; ++j)
            vf[j] = *reinterpret_cast<const short*>(
                qkv + (size_t)(kb + lg * 8 + j) * 384 + 256 + h * 16 + lq);

        // rescale O rows (row q' = lg*4+j) by corr[q']
        #pragma unroll
        for (int j = 0; j < 4; ++j)
            O[j] *= __shfl(corr, lg * 4 + j);

        O = __builtin_amdgcn_mfma_f32_16x16x32_bf16(pa, vf, O, 0, 0, 0);
    }

    // wave partials
    if (l < 16) { mlds[w][0][l] = m; mlds[w][1][l] = lsum; }
    #pragma unroll
    for (int j = 0; j < 4; ++j)
        Olds[w][lg * 4 + j][lq] = O[j];
    __syncthreads();

    // merge: thread t -> (q = t>>4, dh = t&15)
    {
        const int q = t >> 4, dh = t & 15;
        float mg = -INFINITY;
        #pragma unroll
        for (int ww = 0; ww < 4; ++ww) mg = fmaxf(mg, mlds[ww][0][q]);
        float lg2 = 0.f, ov = 0.f;
        #pragma unroll
        for (int ww = 0; ww < 4; ++ww) {
            const float wgt = __expf(mlds[ww][0][q] - mg);
            lg2 += mlds[ww][1][q] * wgt;
            ov  += wgt * Olds[ww][q][dh];
        }
        attn_bf[(size_t)(qt * 16 + q) * D_DIM + h * 16 + dh] =
            __float2bfloat16(ov / lg2);
    }
}

// ---------------------------------------------------------------------------
// tail1: load attn rows + Wo + residual + LN1 + FF1 + FF2-partial.
// grid (64, FF2_KS) = 256 blocks x 512 thr (8 waves). LDS ~34 KB.
// ---------------------------------------------------------------------------
__global__ __launch_bounds__(512) void tail1_kernel(
    const __hip_bfloat16* __restrict__ attn_g,
    const __hip_bfloat16* __restrict__ Wo_i, const float* __restrict__ bo_i,
    const float* __restrict__ x_in, float* __restrict__ x2,
    const float* __restrict__ g, const float* __restrict__ b,
    const __hip_bfloat16* __restrict__ W1_i, const float* __restrict__ b1_i,
    const __hip_bfloat16* __restrict__ W2_i, float* __restrict__ P)
{
    __shared__ __hip_bfloat16 att[16][136];     // attn rows (bf16)
    __shared__ float lds_wo[16][132];           // Wo output (f32)
    __shared__ __hip_bfloat16 xb[16][136];      // post-LN1 rows (bf16)
    __shared__ __hip_bfloat16 h[16][FF_KC + 8]; // FF1 output (bf16)

    const int t    = threadIdx.x;
    const int wave = t >> 6;
    const int lane = t & 63;
    const int lr   = lane & 15;
    const int lk   = (lane >> 4) * 8;
    const int m0   = blockIdx.x * 16;
    const int kb   = blockIdx.y * FF_KC;

    // ---- A: load attn rows (16 x 128 bf16, 4 per thread) ----
    {
        const int e    = t * 4;          // 0..2044
        const int rloc = e >> 7;
        const int col  = e & 127;
        *reinterpret_cast<bf16x4*>(&att[rloc][col]) =
            *reinterpret_cast<const bf16x4*>(
                attn_g + (size_t)(m0 + rloc) * D_DIM + col);
    }
    __syncthreads();

    // ---- B: Wo (8 col-units of 16 over 8 waves = 1 round) ----
    {
        const int n0 = wave * 16;
        f32x4 acc = {};
        const __hip_bfloat16* Wp = Wo_i + (size_t)(n0 + lr) * 128 + lk;
        #pragma unroll
        for (int k = 0; k < 128; k += 32) {
            const bf16x8 a = *reinterpret_cast<const bf16x8*>(&att[lr][lk + k]);
            const bf16x8 bb = *reinterpret_cast<const bf16x8*>(Wp + k);
            acc = __builtin_amdgcn_mfma_f32_16x16x32_bf16(a, bb, acc, 0, 0, 0);
        }
        const int orow = (lane >> 4) * 4;
        const int col  = n0 + lr;
        #pragma unroll
        for (int j = 0; j < 4; ++j)
            lds_wo[orow + j][col] = acc[j];
    }
    __syncthreads();

    // ---- C: residual + LN1 (16 rows over 8 waves = 2 rounds) ----
    #pragma unroll
    for (int rr = 0; rr < 2; ++rr) {
        const int rloc = wave + rr * 8;
        const int d0 = lane * 2;
        const size_t i0 = (size_t)(m0 + rloc) * D_DIM + d0;
        float v0 = x_in[i0]     + lds_wo[rloc][d0]     + bo_i[d0];
        float v1 = x_in[i0 + 1] + lds_wo[rloc][d0 + 1] + bo_i[d0 + 1];
        float s = v0 + v1;
        #pragma unroll
        for (int off = 32; off >= 1; off >>= 1) s += __shfl_xor(s, off);
        const float mu = s * (1.0f / 128.0f);
        const float q0 = v0 - mu, q1 = v1 - mu;
        float qs = q0 * q0 + q1 * q1;
        #pragma unroll
        for (int off = 32; off >= 1; off >>= 1) qs += __shfl_xor(qs, off);
        const float rs = rsqrtf(qs * (1.0f / 128.0f) + LN_EPS);
        const float r0 = q0 * rs * g[d0] + b[d0];
        const float r1 = q1 * rs * g[d0 + 1] + b[d0 + 1];
        x2[i0] = r0;     x2[i0 + 1] = r1;
        xb[rloc][d0] = __float2bfloat16(r0);
        xb[rloc][d0 + 1] = __float2bfloat16(r1);
    }
    __syncthreads();

    // ---- D: FF1 (+bias+ReLU) from LDS xb -> LDS h (16 units / 8 waves) ----
    #pragma unroll
    for (int r = 0; r < 2; ++r) {
        const int n0 = kb + (wave + r * 8) * 32;
        f32x4 acc[2] = {};
        const __hip_bfloat16* Wp = W1_i + (size_t)(n0 + lr) * 128 + lk;
        #pragma unroll
        for (int k = 0; k < 128; k += 32) {
            const bf16x8 a = *reinterpret_cast<const bf16x8*>(&xb[lr][lk + k]);
            #pragma unroll
            for (int nt = 0; nt < 2; ++nt) {
                const bf16x8 bb = *reinterpret_cast<const bf16x8*>(Wp + (size_t)nt * 16 * 128 + k);
                acc[nt] = __builtin_amdgcn_mfma_f32_16x16x32_bf16(a, bb, acc[nt], 0, 0, 0);
            }
        }
        const int orow = (lane >> 4) * 4;
        #pragma unroll
        for (int hh = 0; hh < 2; ++hh) {
            const int colg = n0 + hh * 16 + lr;      // global col (bias)
            const int coll = colg - kb;              // local LDS col
            const float bv = b1_i[colg];
            #pragma unroll
            for (int j = 0; j < 4; ++j)
                h[orow + j][coll] =
                    __float2bfloat16(fmaxf(acc[hh][j] + bv, 0.f));
        }
    }
    __syncthreads();

    // ---- E: FF2 partial [16 x 128], K = FF_KC from LDS -> P[z] ----
    {
        const int n0 = wave * 16;
        f32x4 acc = {};
        const __hip_bfloat16* Wp = W2_i + (size_t)(n0 + lr) * FF_DIM + kb + lk;
        #pragma unroll 4
        for (int k = 0; k < FF_KC; k += 32) {
            const bf16x8 a = *reinterpret_cast<const bf16x8*>(&h[lr][lk + k]);
            const bf16x8 bb = *reinterpret_cast<const bf16x8*>(Wp + k);
            acc = __builtin_amdgcn_mfma_f32_16x16x32_bf16(a, bb, acc, 0, 0, 0);
        }
        float* Pz = P + (size_t)blockIdx.y * (S_LEN * D_DIM);
        const int orow = m0 + (lane >> 4) * 4;
        const int col  = n0 + lr;
        #pragma unroll
        for (int j = 0; j < 4; ++j)
            Pz[(size_t)(orow + j) * D_DIM + col] = acc[j];
    }
}

// ---------------------------------------------------------------------------
// LN2 (+FF2_KS partials + bias) then next-layer QKV (or out-proj if LAST).
// grid (64 m-tiles, NZ) x 256 thr (proven R14/R16).
// ---------------------------------------------------------------------------
template<int LAST>
__global__ __launch_bounds__(256) void ln2_qkv_kernel(
    const float* __restrict__ P, const float* __restrict__ b2_i,
    const float* __restrict__ xr, float* __restrict__ xw,
    const float* __restrict__ g, const float* __restrict__ b,
    const __hip_bfloat16* __restrict__ Wn, const float* __restrict__ bn,
    __hip_bfloat16* __restrict__ qkv_bf, float* __restrict__ out)
{
    __shared__ __hip_bfloat16 xb[16][136];

    const int tid  = threadIdx.x;
    const int wave = tid >> 6;
    const int lane = tid & 63;
    const int lr   = lane & 15;
    const int lk   = (lane >> 4) * 8;
    const int m0   = blockIdx.x * 16;

    // ---- LN2: 16 rows over 4 waves = 4 rounds ----
    #pragma unroll
    for (int rr = 0; rr < 4; ++rr) {
        const int rloc = wave + rr * 4;
        const int d0 = lane * 2;
        const size_t i0 = (size_t)(m0 + rloc) * D_DIM + d0;
        float v0 = xr[i0]     + b2_i[d0];
        float v1 = xr[i0 + 1] + b2_i[d0 + 1];
        #pragma unroll
        for (int p = 0; p < FF2_KS; ++p) {
            v0 += P[(size_t)p * (S_LEN * D_DIM) + i0];
            v1 += P[(size_t)p * (S_LEN * D_DIM) + i0 + 1];
        }
        float s = v0 + v1;
        #pragma unroll
        for (int off = 32; off >= 1; off >>= 1) s += __shfl_xor(s, off);
        const float mu = s * (1.0f / 128.0f);
        const float q0 = v0 - mu, q1 = v1 - mu;
        float qs = q0 * q0 + q1 * q1;
        #pragma unroll
        for (int off = 32; off >= 1; off >>= 1) qs += __shfl_xor(qs, off);
        const float rs = rsqrtf(qs * (1.0f / 128.0f) + LN_EPS);
        const float r0 = q0 * rs * g[d0] + b[d0];
        const float r1 = q1 * rs * g[d0 + 1] + b[d0 + 1];
        xw[i0] = r0;     xw[i0 + 1] = r1;      // replicated: identical values
        xb[rloc][d0] = __float2bfloat16(r0);
        xb[rloc][d0 + 1] = __float2bfloat16(r1);
    }
    __syncthreads();

    // ---- one 16x32 MFMA unit per wave, A from LDS ----
    const int unit = blockIdx.y * 4 + wave;   // 0..11 (QKV) or 0..23 (out)
    const int n0 = unit * 32;
    f32x4 acc[2] = {};
    {
        const __hip_bfloat16* Wp = Wn + (size_t)(n0 + lr) * 128 + lk;
        #pragma unroll
        for (int k = 0; k < 128; k += 32) {
            const bf16x8 a = *reinterpret_cast<const bf16x8*>(&xb[lr][lk + k]);
            #pragma unroll
            for (int nt = 0; nt < 2; ++nt) {
                const bf16x8 bb = *reinterpret_cast<const bf16x8*>(Wp + (size_t)nt * 16 * 128 + k);
                acc[nt] = __builtin_amdgcn_mfma_f32_16x16x32_bf16(a, bb, acc[nt], 0, 0, 0);
            }
        }
    }
    const int orow = m0 + (lane >> 4) * 4;
    if (!LAST) {
        #pragma unroll
        for (int h = 0; h < 2; ++h) {
            const int col = n0 + h * 16 + lr;
            const float bv = bn[col];
            #pragma unroll
            for (int j = 0; j < 4; ++j)
                qkv_bf[(size_t)(orow + j) * 384 + col] =
                    __float2bfloat16(acc[h][j] + bv);
        }
    } else {
        #pragma unroll
        for (int h = 0; h < 2; ++h) {
            const int col = n0 + h * 16 + lr;
            const float bv = bn[col];
            #pragma unroll
            for (int j = 0; j < 4; ++j)
                out[(size_t)(orow + j) * HID_DIM + col] = acc[h][j] + bv;
        }
        if (blockIdx.y == 0 && tid < 16)
            out[(size_t)S_LEN * HID_DIM + m0 + tid] = 0.0f;
    }
}

// ---------------------------------------------------------------------------
// Host launch: 14 dispatches.
// ---------------------------------------------------------------------------
extern "C" void kernel_launch(void* const* d_in, const int* in_sizes, int n_in,
                              void* d_out, int out_size, void* d_ws, size_t ws_size,
                              hipStream_t stream)
{
    const int*   shot    = (const int*)  d_in[0];
    const int*   cam     = (const int*)  d_in[1];
    const int*   light   = (const int*)  d_in[2];
    const int*   tone    = (const int*)  d_in[3];
    const int*   rhythm  = (const int*)  d_in[4];
    const int*   trans   = (const int*)  d_in[5];
    const float* motion  = (const float*)d_in[6];
    const float* focus   = (const float*)d_in[7];
    const float* E_shot  = (const float*)d_in[8];
    const float* E_cam   = (const float*)d_in[9];
    const float* E_light = (const float*)d_in[10];
    const float* E_tone  = (const float*)d_in[11];
    const float* E_rhyth = (const float*)d_in[12];
    const float* E_trans = (const float*)d_in[13];
    const float* W_m1    = (const float*)d_in[14];
    const float* b_m1    = (const float*)d_in[15];
    const float* W_m2    = (const float*)d_in[16];
    const float* b_m2    = (const float*)d_in[17];
    const float* W_f     = (const float*)d_in[18];
    const float* b_f     = (const float*)d_in[19];
    const float* pos     = (const float*)d_in[20];
    const float* Wqkv    = (const float*)d_in[21];
    const float* bqkv    = (const float*)d_in[22];
    const float* Wo      = (const float*)d_in[23];
    const float* bo      = (const float*)d_in[24];
    const float* W1      = (const float*)d_in[25];
    const float* b1      = (const float*)d_in[26];
    const float* W2      = (const float*)d_in[27];
    const float* b2      = (const float*)d_in[28];
    const float* ln1_g   = (const float*)d_in[29];
    const float* ln1_b   = (const float*)d_in[30];
    const float* ln2_g   = (const float*)d_in[31];
    const float* ln2_b   = (const float*)d_in[32];
    const float* W_out   = (const float*)d_in[33];
    const float* b_out   = (const float*)d_in[34];

    float* out = (float*)d_out;

    // workspace layout (ws = 256 MiB, ample)
    float* ws = (float*)d_ws;
    float* x  = ws;                                 // 131072 f32 (pre-LN1 residual)
    float* x2 = x + S_LEN * D_DIM;                  // 131072 f32 (post-LN1 residual)
    float* P  = x2 + S_LEN * D_DIM;                 // 4*131072 (FF2 partials)
    __hip_bfloat16* bfb = (__hip_bfloat16*)(P + FF2_KS * S_LEN * D_DIM);
    __hip_bfloat16* wqkv_bf = bfb;                  // [4][384][128]
    __hip_bfloat16* wo_bf   = wqkv_bf + 196608;     // [4][128][128]
    __hip_bfloat16* w1_bf   = wo_bf   + 65536;      // [4][2048][128]
    __hip_bfloat16* w2_bf   = w1_bf   + 1048576;    // [4][128][2048]
    __hip_bfloat16* wout_bf = w2_bf   + 1048576;    // [768][128]
    __hip_bfloat16* x_bf    = wout_bf + 98304;      // [1024][128] (embed only)
    __hip_bfloat16* qkv_bf  = x_bf    + 131072;     // [1024][384]
    __hip_bfloat16* attn_bf = qkv_bf  + 393216;     // [1024][128]

    // 1) weights -> bf16
    wconv_kernel<<<2400, 256, 0, stream>>>(Wqkv, Wo, W1, W2, W_out, bfb);

    // 2) embed + layer-0 qkv
    embed_qkv_kernel<<<64, 1024, 0, stream>>>(
        shot, cam, light, tone, rhythm, trans, motion, focus,
        E_shot, E_cam, E_light, E_tone, E_rhyth, E_trans,
        W_m1, b_m1, W_m2, b_m2, W_f, b_f, pos,
        wqkv_bf, bqkv, x, x_bf, qkv_bf);

    // 3) layers: 3 dispatches each
    for (int li = 0; li < L_LAYERS; ++li) {
        const __hip_bfloat16* Wo_i = wo_bf + (size_t)li * D_DIM * D_DIM;
        const __hip_bfloat16* W1_i = w1_bf + (size_t)li * FF_DIM * D_DIM;
        const __hip_bfloat16* W2_i = w2_bf + (size_t)li * D_DIM * FF_DIM;
        const float* bo_i = bo + (size_t)li * D_DIM;
        const float* b1_i = b1 + (size_t)li * FF_DIM;
        const float* b2_i = b2 + (size_t)li * D_DIM;
        const float* l1g = ln1_g + (size_t)li * D_DIM;
        const float* l1b = ln1_b + (size_t)li * D_DIM;
        const float* l2g = ln2_g + (size_t)li * D_DIM;
        const float* l2b = ln2_b + (size_t)li * D_DIM;

        attn_mfma_kernel<<<dim3(64, H_HEADS), 256, 0, stream>>>(qkv_bf, attn_bf);

        tail1_kernel<<<dim3(64, FF2_KS), 512, 0, stream>>>(
            attn_bf, Wo_i, bo_i, x, x2, l1g, l1b, W1_i, b1_i, W2_i, P);

        if (li < L_LAYERS - 1) {
            const __hip_bfloat16* Wn = wqkv_bf + (size_t)(li + 1) * 3 * D_DIM * D_DIM;
            const float* bn = bqkv + (size_t)(li + 1) * 3 * D_DIM;
            ln2_qkv_kernel<0><<<dim3(64, 3), 256, 0, stream>>>(
                P, b2_i, x2, x, l2g, l2b, Wn, bn, qkv_bf, nullptr);
        } else {
            ln2_qkv_kernel<1><<<dim3(64, 6), 256, 0, stream>>>(
                P, b2_i, x2, x, l2g, l2b, wout_bf, b_out, nullptr, out);
        }
    }
}